// Round 6
// baseline (136.559 us; speedup 1.0000x reference)
//
#include <hip/hip_runtime.h>
#include <hip/hip_bf16.h>
#include <stdint.h>

#define NPAIRS 500000
#define NNODES 100000
#define DIM    128
#define D2     256

typedef __bf16 bf16;
typedef __bf16 bf16x8 __attribute__((ext_vector_type(8)));
typedef __bf16 bf16x4 __attribute__((ext_vector_type(4)));
typedef float  f32x4  __attribute__((ext_vector_type(4)));

// =================== PHASE 1 PACK ===================
// W1'[k][n'] = n'<256 ? W1[k][n'] (U half, k in 0..127)
//                     : W1[k+128][n'-256] (V half)
// A-operand frags: w1p[((cg*4+kks)*64+lane)*8+j] = W1'[kks*32+lg*8+j][cg*16+l15]
__global__ void pack_w1p(const float* __restrict__ W1, bf16* __restrict__ w1p) {
    int t = blockIdx.x * 256 + threadIdx.x;   // 0..8191
    int lane = t & 63;
    int kks = (t >> 6) & 3;
    int cg  = t >> 8;                          // 0..31
    int l15 = lane & 15, lg = lane >> 4;
    int np = cg * 16 + l15;                    // 0..511
    int k0 = kks * 32 + lg * 8;
    const float* src = (np < D2) ? (W1 + (long)k0 * D2 + np)
                                 : (W1 + (long)(k0 + 128) * D2 + (np - D2));
    bf16x8 v;
#pragma unroll
    for (int j = 0; j < 8; ++j) v[j] = (bf16)src[(long)j * D2];
    *(bf16x8*)((char*)w1p + ((long)t << 4)) = v;
}

// =================== PHASE 1: UV = [X*W1a | X*W1b] ===================
// 128 nodes/block, 8 waves (2 node-groups x 4 hc-groups), hc-loop of 2.
// mfma(A = W1' frag, B = X frag): D col(l15)=node, row(lg*4+r)=hc.
__launch_bounds__(512, 2)
__global__ void gemm_uv(const float* __restrict__ x,
                        const bf16*  __restrict__ w1p,
                        bf16*        __restrict__ UV) {
    __shared__ char xt[128 * 256];   // 32 KB: [128 node][128 k] bf16, 4-bit XOR swizzle
    int tid  = threadIdx.x;
    int wave = tid >> 6, lane = tid & 63;
    int l15 = lane & 15, lg = lane >> 4;
    int wr = wave >> 2, wc = wave & 3;
    long nb = (long)blockIdx.x * 128;

    // stage: fp32 -> bf16, 16 threads cover one 512B fp32 node row (coalesced)
#pragma unroll
    for (int it = 0; it < 4; ++it) {
        int task = it * 512 + tid;          // 0..2047
        int r = task >> 4, c = task & 15;
        long node = nb + r;
        const float* src = x + (node < NNODES ? node : 0) * DIM + c * 8;
        float4 a = ((const float4*)src)[0];
        float4 b = ((const float4*)src)[1];
        bf16x8 v;
        v[0]=(bf16)a.x; v[1]=(bf16)a.y; v[2]=(bf16)a.z; v[3]=(bf16)a.w;
        v[4]=(bf16)b.x; v[5]=(bf16)b.y; v[6]=(bf16)b.z; v[7]=(bf16)b.w;
        *(bf16x8*)(xt + r * 256 + ((c * 16) ^ ((r & 15) << 4))) = v;
    }
    __syncthreads();

#pragma unroll
    for (int h2 = 0; h2 < 2; ++h2) {
        int hcbase = (h2 * 4 + wc) * 64;
        f32x4 acc[4][4];
#pragma unroll
        for (int m = 0; m < 4; ++m)
#pragma unroll
            for (int nf = 0; nf < 4; ++nf)
                acc[m][nf] = (f32x4){0.f, 0.f, 0.f, 0.f};

#pragma unroll
        for (int kks = 0; kks < 4; ++kks) {
            bf16x8 xf[4];
            int kbyte = kks * 64 + lg * 16;
#pragma unroll
            for (int nf = 0; nf < 4; ++nf) {
                int r = wr * 64 + nf * 16 + l15;
                xf[nf] = *(const bf16x8*)(xt + r * 256 + (kbyte ^ ((r & 15) << 4)));
            }
#pragma unroll
            for (int m = 0; m < 4; ++m) {
                int cg = (hcbase >> 4) + m;
                bf16x8 wf = *(const bf16x8*)((const char*)w1p +
                                (((cg * 4 + kks) * 64 + lane) << 4));
#pragma unroll
                for (int nf = 0; nf < 4; ++nf)
                    acc[m][nf] = __builtin_amdgcn_mfma_f32_16x16x32_bf16(wf, xf[nf], acc[m][nf], 0, 0, 0);
            }
        }
#pragma unroll
        for (int m = 0; m < 4; ++m)
#pragma unroll
            for (int nf = 0; nf < 4; ++nf) {
                long node = nb + wr * 64 + nf * 16 + l15;
                if (node < NNODES) {
                    int hc = hcbase + m * 16 + lg * 4;
                    bf16x4 o;
                    o[0] = (bf16)acc[m][nf][0];
                    o[1] = (bf16)acc[m][nf][1];
                    o[2] = (bf16)acc[m][nf][2];
                    o[3] = (bf16)acc[m][nf][3];
                    *(bf16x4*)(UV + node * 512 + hc) = o;
                }
            }
    }
}

// =================== PHASE 2: pred = W2.relu(u_i + v_j + b1) + b2 ===================
// 2 pairs per wave-iter: lanes 0-31 pair A, 32-63 pair B; lane reads 16B of the
// 512B row; in-register add+relu+dot; 5-shfl reduce within each half.
__launch_bounds__(512)
__global__ void pair_pred(const bf16* __restrict__ UV, const int* __restrict__ junc,
                          const float* __restrict__ b1, const float* __restrict__ w2,
                          const float* __restrict__ b2, float* __restrict__ out) {
    int tid = threadIdx.x;
    int lane = tid & 63, half = lane >> 5, l31 = lane & 31;
    long gw = (long)blockIdx.x * 8 + (tid >> 6);   // 0..8191
    float b1c[8], w2c[8];
#pragma unroll
    for (int e = 0; e < 8; ++e) {
        int col = l31 * 8 + e;
        b1c[e] = b1[col];
        w2c[e] = w2[col];
    }
    float b2v = b2[0];
    for (long q = gw; q < NPAIRS / 2; q += 8192) {
        long p = 2 * q + half;
        int2 ij = ((const int2*)junc)[p];
        bf16x8 u = *(const bf16x8*)(UV + (long)ij.x * 512 + l31 * 8);
        bf16x8 v = *(const bf16x8*)(UV + (long)ij.y * 512 + 256 + l31 * 8);
        float s = 0.f;
#pragma unroll
        for (int e = 0; e < 8; ++e) {
            float h = (float)u[e] + (float)v[e] + b1c[e];
            s = fmaf(fmaxf(h, 0.f), w2c[e], s);
        }
        s += __shfl_xor(s, 1);
        s += __shfl_xor(s, 2);
        s += __shfl_xor(s, 4);
        s += __shfl_xor(s, 8);
        s += __shfl_xor(s, 16);
        if (l31 == 0) out[p] = s + b2v;
    }
}

// =================== FALLBACK (small ws): fused, known-correct ===================
__global__ void pack_w1(const float* __restrict__ W1, bf16* __restrict__ w1f) {
    int t = blockIdx.x * 256 + threadIdx.x;   // 0..8191
    int lane = t & 63;
    int kk = (t >> 6) & 7;
    int cg = t >> 9;
    int l15 = lane & 15, lg = lane >> 4;
    bf16x8 v;
#pragma unroll
    for (int j = 0; j < 8; ++j)
        v[j] = (bf16)W1[(long)(kk * 32 + lg * 8 + j) * D2 + cg * 16 + l15];
    *(bf16x8*)((char*)w1f + ((long)t << 4)) = v;
}

__launch_bounds__(512, 2)
__global__ void fused_fb(const float* __restrict__ x, const int* __restrict__ junc,
                         const bf16* __restrict__ w1f, const float* __restrict__ b1,
                         const float* __restrict__ w2p, const float* __restrict__ b2,
                         float* __restrict__ out) {
    __shared__ char  atile[128 * 512];
    __shared__ float outp[4][128];
    int tid  = threadIdx.x;
    int wave = tid >> 6, lane = tid & 63;
    int l15 = lane & 15, lg = lane >> 4;
    int wr = wave >> 2, wc = wave & 3;
    long base_p = (long)blockIdx.x * 128;

    float bb[4][4], ww[4][4];
#pragma unroll
    for (int m = 0; m < 4; ++m)
#pragma unroll
        for (int r = 0; r < 4; ++r) {
            int hc = wc * 64 + m * 16 + lg * 4 + r;
            bb[m][r] = b1[hc];
            ww[m][r] = w2p[hc];
        }
#pragma unroll
    for (int it = 0; it < 8; ++it) {
        int task  = it * 512 + tid;
        int nr = task >> 4, chunk = task & 15;
        int r = nr >> 1, side = nr & 1;
        long p = base_p + r;
        int idx = (p < NPAIRS) ? junc[p * 2 + side] : 0;
        const float4* src = (const float4*)(x + (long)idx * DIM + chunk * 8);
        float4 a = src[0], b = src[1];
        bf16x8 v;
        v[0]=(bf16)a.x; v[1]=(bf16)a.y; v[2]=(bf16)a.z; v[3]=(bf16)a.w;
        v[4]=(bf16)b.x; v[5]=(bf16)b.y; v[6]=(bf16)b.z; v[7]=(bf16)b.w;
        int bir = side * 256 + chunk * 16;
        *(bf16x8*)(atile + r * 512 + (bir ^ ((r & 31) << 4))) = v;
    }
    __syncthreads();

    f32x4 acc[4][4];
#pragma unroll
    for (int m = 0; m < 4; ++m)
#pragma unroll
        for (int n = 0; n < 4; ++n)
            acc[m][n] = (f32x4){0.f, 0.f, 0.f, 0.f};
#pragma unroll
    for (int kk = 0; kk < 8; ++kk) {
        bf16x8 xf[4];
        int kbyte = kk * 64 + lg * 16;
#pragma unroll
        for (int n = 0; n < 4; ++n) {
            int r = wr * 64 + n * 16 + l15;
            xf[n] = *(const bf16x8*)(atile + r * 512 + (kbyte ^ ((r & 31) << 4)));
        }
#pragma unroll
        for (int m = 0; m < 4; ++m) {
            bf16x8 wf = *(const bf16x8*)((const char*)w1f +
                            ((((wc * 4 + m) * 8 + kk) * 64 + lane) << 4));
#pragma unroll
            for (int n = 0; n < 4; ++n)
                acc[m][n] = __builtin_amdgcn_mfma_f32_16x16x32_bf16(wf, xf[n], acc[m][n], 0, 0, 0);
        }
    }
#pragma unroll
    for (int n = 0; n < 4; ++n) {
        float s = 0.f;
#pragma unroll
        for (int m = 0; m < 4; ++m)
#pragma unroll
            for (int r = 0; r < 4; ++r)
                s = fmaf(fmaxf(acc[m][n][r] + bb[m][r], 0.f), ww[m][r], s);
        s += __shfl_xor(s, 16);
        s += __shfl_xor(s, 32);
        if (lg == 0) outp[wc][wr * 64 + n * 16 + l15] = s;
    }
    __syncthreads();
    if (tid < 128) {
        long p = base_p + tid;
        if (p < NPAIRS)
            out[p] = b2[0] + outp[0][tid] + outp[1][tid] + outp[2][tid] + outp[3][tid];
    }
}

extern "C" void kernel_launch(void* const* d_in, const int* in_sizes, int n_in,
                              void* d_out, int out_size, void* d_ws, size_t ws_size,
                              hipStream_t stream) {
    const float* x    = (const float*)d_in[0];
    const int*   junc = (const int*)  d_in[1];
    const float* W1   = (const float*)d_in[2];
    const float* b1   = (const float*)d_in[3];
    const float* W2   = (const float*)d_in[4];
    const float* b2   = (const float*)d_in[5];
    float* out = (float*)d_out;

    const size_t UV_BYTES = (size_t)NNODES * 512 * 2;    // 102,400,000
    const size_t NEED     = UV_BYTES + 131072;

    if (ws_size >= NEED) {
        bf16* UV  = (bf16*)d_ws;
        bf16* w1p = (bf16*)((char*)d_ws + UV_BYTES);
        hipLaunchKernelGGL(pack_w1p, dim3(32), dim3(256), 0, stream, W1, w1p);
        hipLaunchKernelGGL(gemm_uv, dim3((NNODES + 127) / 128), dim3(512), 0, stream,
                           x, w1p, UV);
        hipLaunchKernelGGL(pair_pred, dim3(1024), dim3(512), 0, stream,
                           UV, junc, b1, W2, b2, out);
    } else {
        bf16* w1f = (bf16*)d_ws;
        hipLaunchKernelGGL(pack_w1, dim3(32), dim3(256), 0, stream, W1, w1f);
        hipLaunchKernelGGL(fused_fb, dim3((NPAIRS + 127) / 128), dim3(512), 0, stream,
                           x, junc, w1f, b1, W2, b2, out);
    }
}

// Round 7
// 126.246 us; speedup vs baseline: 1.0817x; 1.0817x over previous
//
#include <hip/hip_runtime.h>
#include <hip/hip_bf16.h>
#include <stdint.h>

#define NPAIRS 500000
#define NNODES 100000
#define DIM    128
#define D2     256

typedef __bf16 bf16;
typedef __bf16 bf16x8 __attribute__((ext_vector_type(8)));
typedef __bf16 bf16x4 __attribute__((ext_vector_type(4)));
typedef float  f32x4  __attribute__((ext_vector_type(4)));

// =================== PHASE 1 PACK ===================
// W1'[k][n'] = n'<256 ? W1[k][n'] (U half, k in 0..127)
//                     : W1[k+128][n'-256] (V half)
// A-operand frags: w1p[((cg*4+kks)*64+lane)*8+j] = W1'[kks*32+lg*8+j][cg*16+l15]
__global__ void pack_w1p(const float* __restrict__ W1, bf16* __restrict__ w1p) {
    int t = blockIdx.x * 256 + threadIdx.x;   // 0..8191
    int lane = t & 63;
    int kks = (t >> 6) & 3;
    int cg  = t >> 8;                          // 0..31
    int l15 = lane & 15, lg = lane >> 4;
    int np = cg * 16 + l15;                    // 0..511
    int k0 = kks * 32 + lg * 8;
    const float* src = (np < D2) ? (W1 + (long)k0 * D2 + np)
                                 : (W1 + (long)(k0 + 128) * D2 + (np - D2));
    bf16x8 v;
#pragma unroll
    for (int j = 0; j < 8; ++j) v[j] = (bf16)src[(long)j * D2];
    *(bf16x8*)((char*)w1p + ((long)t << 4)) = v;
}

// =================== PHASE 1: UV = [X*W1a | X*W1b] ===================
// 128 nodes/block, 8 waves (2 node-groups x 4 hc-groups), hc-loop of 2.
// mfma(A = W1' frag, B = X frag): D col(l15)=node, row(lg*4+r)=hc.
// Store path: acc -> swizzled LDS hs -> coalesced bf16x8 row stores.
__launch_bounds__(512, 2)
__global__ void gemm_uv(const float* __restrict__ x,
                        const bf16*  __restrict__ w1p,
                        bf16*        __restrict__ UV) {
    __shared__ char xt[128 * 256];   // 32 KB: [128 node][128 k] bf16, XOR swizzle
    __shared__ char hs[128 * 512];   // 64 KB: [128 node][256 hc] bf16 (one half)
    int tid  = threadIdx.x;
    int wave = tid >> 6, lane = tid & 63;
    int l15 = lane & 15, lg = lane >> 4;
    int wr = wave >> 2, wc = wave & 3;
    long nb = (long)blockIdx.x * 128;

    // stage: fp32 -> bf16, 16 threads cover one 512B fp32 node row (coalesced)
#pragma unroll
    for (int it = 0; it < 4; ++it) {
        int task = it * 512 + tid;          // 0..2047
        int r = task >> 4, c = task & 15;
        long node = nb + r;
        const float* src = x + (node < NNODES ? node : 0) * DIM + c * 8;
        float4 a = ((const float4*)src)[0];
        float4 b = ((const float4*)src)[1];
        bf16x8 v;
        v[0]=(bf16)a.x; v[1]=(bf16)a.y; v[2]=(bf16)a.z; v[3]=(bf16)a.w;
        v[4]=(bf16)b.x; v[5]=(bf16)b.y; v[6]=(bf16)b.z; v[7]=(bf16)b.w;
        *(bf16x8*)(xt + r * 256 + ((c * 16) ^ ((r & 15) << 4))) = v;
    }
    __syncthreads();

#pragma unroll 1
    for (int h2 = 0; h2 < 2; ++h2) {
        int hcbase = (h2 * 4 + wc) * 64;
        f32x4 acc[4][4];
#pragma unroll
        for (int m = 0; m < 4; ++m)
#pragma unroll
            for (int nf = 0; nf < 4; ++nf)
                acc[m][nf] = (f32x4){0.f, 0.f, 0.f, 0.f};

#pragma unroll
        for (int kks = 0; kks < 4; ++kks) {
            bf16x8 xf[4];
            int kbyte = kks * 64 + lg * 16;
#pragma unroll
            for (int nf = 0; nf < 4; ++nf) {
                int r = wr * 64 + nf * 16 + l15;
                xf[nf] = *(const bf16x8*)(xt + r * 256 + (kbyte ^ ((r & 15) << 4)));
            }
#pragma unroll
            for (int m = 0; m < 4; ++m) {
                int cg = (hcbase >> 4) + m;
                bf16x8 wf = *(const bf16x8*)((const char*)w1p +
                                (((cg * 4 + kks) * 64 + lane) << 4));
#pragma unroll
                for (int nf = 0; nf < 4; ++nf)
                    acc[m][nf] = __builtin_amdgcn_mfma_f32_16x16x32_bf16(wf, xf[nf], acc[m][nf], 0, 0, 0);
            }
        }

        // protect hs from previous iteration's store-phase readers
        __syncthreads();
        // dump acc -> hs (bf16, XOR-swizzled within the 512B node-row)
#pragma unroll
        for (int m = 0; m < 4; ++m)
#pragma unroll
            for (int nf = 0; nf < 4; ++nf) {
                int row  = wr * 64 + nf * 16 + l15;
                int col8 = wc * 128 + m * 32 + lg * 8;   // byte offset in row
                bf16x4 o;
                o[0] = (bf16)acc[m][nf][0];
                o[1] = (bf16)acc[m][nf][1];
                o[2] = (bf16)acc[m][nf][2];
                o[3] = (bf16)acc[m][nf][3];
                *(bf16x4*)(hs + row * 512 + (col8 ^ ((row & 31) << 4))) = o;
            }
        __syncthreads();
        // coalesced store: wave covers 2 node-rows x 512B contiguous
#pragma unroll
        for (int it = 0; it < 8; ++it) {
            int chunk = it * 512 + tid;     // 0..4095
            int row = chunk >> 5, c = chunk & 31;
            bf16x8 v = *(const bf16x8*)(hs + row * 512 + ((c * 16) ^ ((row & 31) << 4)));
            long node = nb + row;
            if (node < NNODES)
                *(bf16x8*)(UV + node * 512 + h2 * 256 + c * 8) = v;
        }
    }
}

// =================== PHASE 2: pred = W2.relu(u_i + v_j + b1) + b2 ===================
// 2 pairs per wave (lane halves), 2-deep grid-stride software pipeline:
// 4 independent 16B loads in flight before the first consume.
__launch_bounds__(512)
__global__ void pair_pred(const bf16* __restrict__ UV, const int* __restrict__ junc,
                          const float* __restrict__ b1, const float* __restrict__ w2,
                          const float* __restrict__ b2, float* __restrict__ out) {
    int tid = threadIdx.x;
    int lane = tid & 63, half = lane >> 5, l31 = lane & 31;
    long gw = (long)blockIdx.x * 8 + (tid >> 6);   // 0..8191
    float b1c[8], w2c[8];
#pragma unroll
    for (int e = 0; e < 8; ++e) {
        int col = l31 * 8 + e;
        b1c[e] = b1[col];
        w2c[e] = w2[col];
    }
    float b2v = b2[0];
    const long HALF = NPAIRS / 2;     // 250000
    for (long q = gw; q < HALF; q += 16384) {
        long q2 = q + 8192;
        bool has2 = (q2 < HALF);
        long p0 = 2 * q + half;
        long p1 = has2 ? (2 * q2 + half) : p0;
        int2 ij0 = ((const int2*)junc)[p0];
        int2 ij1 = ((const int2*)junc)[p1];
        bf16x8 u0 = *(const bf16x8*)(UV + (long)ij0.x * 512 + l31 * 8);
        bf16x8 v0 = *(const bf16x8*)(UV + (long)ij0.y * 512 + 256 + l31 * 8);
        bf16x8 u1 = *(const bf16x8*)(UV + (long)ij1.x * 512 + l31 * 8);
        bf16x8 v1 = *(const bf16x8*)(UV + (long)ij1.y * 512 + 256 + l31 * 8);

        float s0 = 0.f, s1 = 0.f;
#pragma unroll
        for (int e = 0; e < 8; ++e) {
            float h0 = (float)u0[e] + (float)v0[e] + b1c[e];
            s0 = fmaf(fmaxf(h0, 0.f), w2c[e], s0);
        }
#pragma unroll
        for (int e = 0; e < 8; ++e) {
            float h1 = (float)u1[e] + (float)v1[e] + b1c[e];
            s1 = fmaf(fmaxf(h1, 0.f), w2c[e], s1);
        }
        s0 += __shfl_xor(s0, 1);  s1 += __shfl_xor(s1, 1);
        s0 += __shfl_xor(s0, 2);  s1 += __shfl_xor(s1, 2);
        s0 += __shfl_xor(s0, 4);  s1 += __shfl_xor(s1, 4);
        s0 += __shfl_xor(s0, 8);  s1 += __shfl_xor(s1, 8);
        s0 += __shfl_xor(s0, 16); s1 += __shfl_xor(s1, 16);
        if (l31 == 0) {
            out[p0] = s0 + b2v;
            if (has2) out[p1] = s1 + b2v;
        }
    }
}

// =================== FALLBACK (small ws): fused, known-correct ===================
__global__ void pack_w1(const float* __restrict__ W1, bf16* __restrict__ w1f) {
    int t = blockIdx.x * 256 + threadIdx.x;   // 0..8191
    int lane = t & 63;
    int kk = (t >> 6) & 7;
    int cg = t >> 9;
    int l15 = lane & 15, lg = lane >> 4;
    bf16x8 v;
#pragma unroll
    for (int j = 0; j < 8; ++j)
        v[j] = (bf16)W1[(long)(kk * 32 + lg * 8 + j) * D2 + cg * 16 + l15];
    *(bf16x8*)((char*)w1f + ((long)t << 4)) = v;
}

__launch_bounds__(512, 2)
__global__ void fused_fb(const float* __restrict__ x, const int* __restrict__ junc,
                         const bf16* __restrict__ w1f, const float* __restrict__ b1,
                         const float* __restrict__ w2p, const float* __restrict__ b2,
                         float* __restrict__ out) {
    __shared__ char  atile[128 * 512];
    __shared__ float outp[4][128];
    int tid  = threadIdx.x;
    int wave = tid >> 6, lane = tid & 63;
    int l15 = lane & 15, lg = lane >> 4;
    int wr = wave >> 2, wc = wave & 3;
    long base_p = (long)blockIdx.x * 128;

    float bb[4][4], ww[4][4];
#pragma unroll
    for (int m = 0; m < 4; ++m)
#pragma unroll
        for (int r = 0; r < 4; ++r) {
            int hc = wc * 64 + m * 16 + lg * 4 + r;
            bb[m][r] = b1[hc];
            ww[m][r] = w2p[hc];
        }
#pragma unroll
    for (int it = 0; it < 8; ++it) {
        int task  = it * 512 + tid;
        int nr = task >> 4, chunk = task & 15;
        int r = nr >> 1, side = nr & 1;
        long p = base_p + r;
        int idx = (p < NPAIRS) ? junc[p * 2 + side] : 0;
        const float4* src = (const float4*)(x + (long)idx * DIM + chunk * 8);
        float4 a = src[0], b = src[1];
        bf16x8 v;
        v[0]=(bf16)a.x; v[1]=(bf16)a.y; v[2]=(bf16)a.z; v[3]=(bf16)a.w;
        v[4]=(bf16)b.x; v[5]=(bf16)b.y; v[6]=(bf16)b.z; v[7]=(bf16)b.w;
        int bir = side * 256 + chunk * 16;
        *(bf16x8*)(atile + r * 512 + (bir ^ ((r & 31) << 4))) = v;
    }
    __syncthreads();

    f32x4 acc[4][4];
#pragma unroll
    for (int m = 0; m < 4; ++m)
#pragma unroll
        for (int n = 0; n < 4; ++n)
            acc[m][n] = (f32x4){0.f, 0.f, 0.f, 0.f};
#pragma unroll
    for (int kk = 0; kk < 8; ++kk) {
        bf16x8 xf[4];
        int kbyte = kk * 64 + lg * 16;
#pragma unroll
        for (int n = 0; n < 4; ++n) {
            int r = wr * 64 + n * 16 + l15;
            xf[n] = *(const bf16x8*)(atile + r * 512 + (kbyte ^ ((r & 31) << 4)));
        }
#pragma unroll
        for (int m = 0; m < 4; ++m) {
            bf16x8 wf = *(const bf16x8*)((const char*)w1f +
                            ((((wc * 4 + m) * 8 + kk) * 64 + lane) << 4));
#pragma unroll
            for (int n = 0; n < 4; ++n)
                acc[m][n] = __builtin_amdgcn_mfma_f32_16x16x32_bf16(wf, xf[n], acc[m][n], 0, 0, 0);
        }
    }
#pragma unroll
    for (int n = 0; n < 4; ++n) {
        float s = 0.f;
#pragma unroll
        for (int m = 0; m < 4; ++m)
#pragma unroll
            for (int r = 0; r < 4; ++r)
                s = fmaf(fmaxf(acc[m][n][r] + bb[m][r], 0.f), ww[m][r], s);
        s += __shfl_xor(s, 16);
        s += __shfl_xor(s, 32);
        if (lg == 0) outp[wc][wr * 64 + n * 16 + l15] = s;
    }
    __syncthreads();
    if (tid < 128) {
        long p = base_p + tid;
        if (p < NPAIRS)
            out[p] = b2[0] + outp[0][tid] + outp[1][tid] + outp[2][tid] + outp[3][tid];
    }
}

extern "C" void kernel_launch(void* const* d_in, const int* in_sizes, int n_in,
                              void* d_out, int out_size, void* d_ws, size_t ws_size,
                              hipStream_t stream) {
    const float* x    = (const float*)d_in[0];
    const int*   junc = (const int*)  d_in[1];
    const float* W1   = (const float*)d_in[2];
    const float* b1   = (const float*)d_in[3];
    const float* W2   = (const float*)d_in[4];
    const float* b2   = (const float*)d_in[5];
    float* out = (float*)d_out;

    const size_t UV_BYTES = (size_t)NNODES * 512 * 2;    // 102,400,000
    const size_t NEED     = UV_BYTES + 131072;

    if (ws_size >= NEED) {
        bf16* UV  = (bf16*)d_ws;
        bf16* w1p = (bf16*)((char*)d_ws + UV_BYTES);
        hipLaunchKernelGGL(pack_w1p, dim3(32), dim3(256), 0, stream, W1, w1p);
        hipLaunchKernelGGL(gemm_uv, dim3((NNODES + 127) / 128), dim3(512), 0, stream,
                           x, w1p, UV);
        hipLaunchKernelGGL(pair_pred, dim3(1024), dim3(512), 0, stream,
                           UV, junc, b1, W2, b2, out);
    } else {
        bf16* w1f = (bf16*)d_ws;
        hipLaunchKernelGGL(pack_w1, dim3(32), dim3(256), 0, stream, W1, w1f);
        hipLaunchKernelGGL(fused_fb, dim3((NPAIRS + 127) / 128), dim3(512), 0, stream,
                           x, junc, w1f, b1, W2, b2, out);
    }
}